// Round 1
// 720.559 us; speedup vs baseline: 1.1960x; 1.1960x over previous
//
#include <hip/hip_runtime.h>
#include <stdint.h>
#include <stddef.h>

#define NN 50000
#define EE 800000
#define GG 64
#define DD 64
#define HH 256

typedef float f32x4 __attribute__((ext_vector_type(4)));
typedef short s16x8 __attribute__((ext_vector_type(8)));
typedef short s16x4 __attribute__((ext_vector_type(4)));

__device__ __forceinline__ short f2bf(float f) {
    union { float f; unsigned u; } v; v.f = f;
    return (short)((v.u + 0x7FFFu + ((v.u >> 16) & 1u)) >> 16);
}

// ---------------- weight prep: transpose to [n][k] + bf16 ----------------
__global__ void prep_weights(const float* __restrict__ eW1, const float* __restrict__ eW2,
                             const float* __restrict__ nW1, const float* __restrict__ nW2,
                             short* __restrict__ W1t, short* __restrict__ W2t,
                             short* __restrict__ NW1t, short* __restrict__ NW2t) {
    int idx = blockIdx.x * blockDim.x + threadIdx.x;   // grid covers 65536
    {
        int n = idx >> 8, k = idx & 255;
        W1t[idx] = f2bf(eW1[k * 256 + n]);
    }
    if (idx < 49152) {
        int n = idx / 192, k = idx - n * 192;
        NW1t[idx] = f2bf(nW1[k * 256 + n]);
    }
    if (idx < 16384) {
        int n = idx >> 8, k = idx & 255;
        W2t[idx]  = f2bf(eW2[k * 64 + n]);
        NW2t[idx] = f2bf(nW2[k * 64 + n]);
    }
}

#define SA1 264   // padded LDS stride (K=256 + 8 bf16)
#define SAN 200   // padded LDS stride for node A (K=192 + 8)

// ---------------- edge kernel: ef_new = MLP([ef, nf[src], nf[dst], u[egid]]) ----------------
// Wave-per-segment coalesced gather; wave-parallel epilogue (stores + atomics + seg-reduce).
__global__ __launch_bounds__(256, 4) void edge_kernel(
    const float* __restrict__ nf, const float* __restrict__ ef, const float* __restrict__ u,
    const int* __restrict__ src, const int* __restrict__ dst, const int* __restrict__ egid,
    const short* __restrict__ W1t, const float* __restrict__ b1,
    const short* __restrict__ W2t, const float* __restrict__ b2,
    float* __restrict__ ef_new, float* __restrict__ agg_m, float* __restrict__ e_aggr)
{
    __shared__ __align__(16) short As[64 * SA1];   // A tile / Y1 tile / Y2 fp32 overlay
    __shared__ int dstS[64];
    __shared__ int gidS[64];
    __shared__ float redS[4][64];

    const int t = threadIdx.x;
    const int e0 = blockIdx.x * 64;
    const int wave = t >> 6, lane = t & 63;
    const int l15 = lane & 15, lq = lane >> 4;

    // ---- per-wave index prefetch (one coalesced load of 64 ints per wave)
    int idxv;
    if (wave == 0)      idxv = e0 + lane;                 // ef rows: identity
    else if (wave == 1) idxv = src[e0 + lane];
    else if (wave == 2) { idxv = dst[e0 + lane]; dstS[lane] = idxv; }
    else                { idxv = egid[e0 + lane]; gidS[lane] = idxv; }

    const float* segbase = (wave == 0) ? ef : (wave == 3) ? u : nf;

    // ---- gather: wave w loads segment w for all 64 rows.
    // 16 lanes cover one row's 64 floats (256B contiguous); 4 rows per instruction.
    {
        const int rsub = lane >> 4;        // 0..3
        const int c4 = (lane & 15) * 4;    // float offset within segment
        #pragma unroll
        for (int r = 0; r < 16; ++r) {
            const int row = r * 4 + rsub;
            const float* sp = segbase + (size_t)__shfl(idxv, row) * 64 + c4;
            f32x4 v = *(const f32x4*)sp;
            s16x4 h = { f2bf(v.x), f2bf(v.y), f2bf(v.z), f2bf(v.w) };
            *(s16x4*)(As + row * SA1 + wave * 64 + c4) = h;
        }
    }
    __syncthreads();

    // ---- phase 1: Y1[64x256] = A @ W1 ; wave w owns cols [w*64, w*64+64)
    f32x4 acc[4][4] = {};
    const short* aB = As + l15 * SA1 + lq * 8;
    const short* bB = W1t + (size_t)(wave * 64 + l15) * 256 + lq * 8;
    #pragma unroll
    for (int kk = 0; kk < 8; ++kk) {
        s16x8 a[4], b[4];
        #pragma unroll
        for (int rt = 0; rt < 4; ++rt) a[rt] = *(const s16x8*)(aB + rt * 16 * SA1 + kk * 32);
        #pragma unroll
        for (int ct = 0; ct < 4; ++ct) b[ct] = *(const s16x8*)(bB + (size_t)ct * 16 * 256 + kk * 32);
        #pragma unroll
        for (int rt = 0; rt < 4; ++rt)
            #pragma unroll
            for (int ct = 0; ct < 4; ++ct)
                acc[rt][ct] = __builtin_amdgcn_mfma_f32_16x16x32_bf16(a[rt], b[ct], acc[rt][ct], 0, 0, 0);
    }
    __syncthreads();   // all A reads done before overwrite

    // ---- Y1 = relu(acc + b1) -> bf16 back into As
    #pragma unroll
    for (int ct = 0; ct < 4; ++ct) {
        int col = wave * 64 + ct * 16 + l15;
        float bb = b1[col];
        #pragma unroll
        for (int rt = 0; rt < 4; ++rt)
            #pragma unroll
            for (int r = 0; r < 4; ++r) {
                int rr = rt * 16 + lq * 4 + r;
                float v = acc[rt][ct][r] + bb;
                As[rr * SA1 + col] = f2bf(v > 0.f ? v : 0.f);
            }
    }
    __syncthreads();

    // ---- phase 2: Y2[64x64] = Y1 @ W2 ; wave w owns cols [w*16, w*16+16)
    f32x4 acc2[4] = {};
    const short* aB2 = As + l15 * SA1 + lq * 8;
    const short* bB2 = W2t + (size_t)(wave * 16 + l15) * 256 + lq * 8;
    #pragma unroll
    for (int kk = 0; kk < 8; ++kk) {
        s16x8 b = *(const s16x8*)(bB2 + kk * 32);
        #pragma unroll
        for (int rt = 0; rt < 4; ++rt) {
            s16x8 a = *(const s16x8*)(aB2 + rt * 16 * SA1 + kk * 32);
            acc2[rt] = __builtin_amdgcn_mfma_f32_16x16x32_bf16(a, b, acc2[rt], 0, 0, 0);
        }
    }
    __syncthreads();   // all Y1 reads done before Y2 overlay

    // ---- Y2 (+bias) into LDS fp32 overlay
    float* Y2s = (float*)As;          // [64][65]
    {
        const int colo = wave * 16 + l15;
        const float bo = b2[colo];
        #pragma unroll
        for (int rt = 0; rt < 4; ++rt)
            #pragma unroll
            for (int r = 0; r < 4; ++r) {
                int rr = rt * 16 + lq * 4 + r;
                Y2s[rr * 65 + colo] = acc2[rt][r] + bo;
            }
    }
    __syncthreads();

    // ---- wave-parallel epilogue: wave w handles rows [w*16, w*16+16)
    // per-row 256B-contiguous store + 256B-contiguous atomic scatter; col-partials for e_aggr.
    const bool uni = (gidS[0] == gidS[63]);   // sorted egid -> uniform iff endpoints match
    float ps = 0.f;
    #pragma unroll
    for (int r = 0; r < 16; ++r) {
        int row = wave * 16 + r;
        float v = Y2s[row * 65 + lane];
        __builtin_nontemporal_store(v, &ef_new[(size_t)(e0 + row) * 64 + lane]);
        atomicAdd(&agg_m[(size_t)dstS[row] * 64 + lane], v);
        ps += v;
    }
    if (uni) redS[wave][lane] = ps;
    __syncthreads();

    if (uni) {
        if (wave == 0) {
            float s = redS[0][lane] + redS[1][lane] + redS[2][lane] + redS[3][lane];
            atomicAdd(&e_aggr[gidS[0] * 64 + lane], s);
        }
    } else if (t < 64) {
        // rare path: group boundary inside block
        float sum = 0.f; int g = gidS[0];
        for (int rr = 0; rr < 64; ++rr) {
            int gg = gidS[rr];
            if (gg != g) { atomicAdd(&e_aggr[g * 64 + t], sum); sum = 0.f; g = gg; }
            sum += Y2s[rr * 65 + t];
        }
        atomicAdd(&e_aggr[g * 64 + t], sum);
    }
}

// ---------------- node kernel: nf_new = MLP([agg_m, nf, u[ngid]]) ----------------
__global__ __launch_bounds__(256, 2) void node_kernel(
    const float* __restrict__ nf, const float* __restrict__ u,
    const int* __restrict__ ngid, const float* __restrict__ agg_m,
    const short* __restrict__ W1t, const float* __restrict__ b1,
    const short* __restrict__ W2t, const float* __restrict__ b2,
    float* __restrict__ nf_new, float* __restrict__ n_aggr)
{
    __shared__ __align__(16) short As[64 * SA1];
    __shared__ int gidS[64];

    const int t = threadIdx.x;
    const int n0 = blockIdx.x * 64;

    {
        const int row = t >> 2, q = t & 3;
        const int i = n0 + row;
        const bool valid = i < NN;
        int g = valid ? ngid[i] : -1;
        if (q == 0) gidS[row] = g;
        short* arow = As + row * SAN;
        if (valid) {
            #pragma unroll
            for (int c4 = q * 48; c4 < q * 48 + 48; c4 += 4) {
                int seg = c4 >> 6, off = c4 & 63;
                const float* p = (seg == 0) ? (agg_m + (size_t)i * 64 + off)
                              : (seg == 1) ? (nf + (size_t)i * 64 + off)
                                           : (u + (size_t)g * 64 + off);
                f32x4 v = *(const f32x4*)p;
                s16x4 h = { f2bf(v.x), f2bf(v.y), f2bf(v.z), f2bf(v.w) };
                *(s16x4*)(arow + c4) = h;
            }
        } else {
            s16x4 z = {0, 0, 0, 0};
            #pragma unroll
            for (int c4 = q * 48; c4 < q * 48 + 48; c4 += 4)
                *(s16x4*)(arow + c4) = z;
        }
    }
    __syncthreads();

    const int wave = t >> 6, lane = t & 63;
    const int l15 = lane & 15, lq = lane >> 4;

    // phase 1: K=192
    f32x4 acc[4][4] = {};
    const short* aB = As + l15 * SAN + lq * 8;
    const short* bB = W1t + (size_t)(wave * 64 + l15) * 192 + lq * 8;
    #pragma unroll
    for (int kk = 0; kk < 6; ++kk) {
        s16x8 a[4], b[4];
        #pragma unroll
        for (int rt = 0; rt < 4; ++rt) a[rt] = *(const s16x8*)(aB + rt * 16 * SAN + kk * 32);
        #pragma unroll
        for (int ct = 0; ct < 4; ++ct) b[ct] = *(const s16x8*)(bB + (size_t)ct * 16 * 192 + kk * 32);
        #pragma unroll
        for (int rt = 0; rt < 4; ++rt)
            #pragma unroll
            for (int ct = 0; ct < 4; ++ct)
                acc[rt][ct] = __builtin_amdgcn_mfma_f32_16x16x32_bf16(a[rt], b[ct], acc[rt][ct], 0, 0, 0);
    }
    __syncthreads();

    #pragma unroll
    for (int ct = 0; ct < 4; ++ct) {
        int col = wave * 64 + ct * 16 + l15;
        float bb = b1[col];
        #pragma unroll
        for (int rt = 0; rt < 4; ++rt)
            #pragma unroll
            for (int r = 0; r < 4; ++r) {
                int rr = rt * 16 + lq * 4 + r;
                float v = acc[rt][ct][r] + bb;
                As[rr * SA1 + col] = f2bf(v > 0.f ? v : 0.f);
            }
    }
    __syncthreads();

    // phase 2: K=256
    f32x4 acc2[4] = {};
    const short* aB2 = As + l15 * SA1 + lq * 8;
    const short* bB2 = W2t + (size_t)(wave * 16 + l15) * 256 + lq * 8;
    #pragma unroll
    for (int kk = 0; kk < 8; ++kk) {
        s16x8 b = *(const s16x8*)(bB2 + kk * 32);
        #pragma unroll
        for (int rt = 0; rt < 4; ++rt) {
            s16x8 a = *(const s16x8*)(aB2 + rt * 16 * SA1 + kk * 32);
            acc2[rt] = __builtin_amdgcn_mfma_f32_16x16x32_bf16(a, b, acc2[rt], 0, 0, 0);
        }
    }
    __syncthreads();

    float* Y2s = (float*)As;
    const int colo = wave * 16 + l15;
    const float bo = b2[colo];
    #pragma unroll
    for (int rt = 0; rt < 4; ++rt)
        #pragma unroll
        for (int r = 0; r < 4; ++r) {
            int rr = rt * 16 + lq * 4 + r;
            float v = acc2[rt][r] + bo;
            bool ok = (n0 + rr) < NN;
            if (ok) nf_new[(size_t)(n0 + rr) * 64 + colo] = v;
            Y2s[rr * 65 + colo] = ok ? v : 0.f;
        }
    __syncthreads();

    if (t < 64) {
        float sum = 0.f; int g = gidS[0];
        for (int rr = 0; rr < 64; ++rr) {
            int gg = gidS[rr];
            if (gg != g) {
                if (g >= 0) atomicAdd(&n_aggr[g * 64 + t], sum);
                sum = 0.f; g = gg;
            }
            sum += Y2s[rr * 65 + t];
        }
        if (g >= 0) atomicAdd(&n_aggr[g * 64 + t], sum);
    }
}

// ---------------- global kernel: u_new = MLP([e_aggr, n_aggr, u]) (fp32, tiny) ----------------
__global__ void global_kernel(const float* __restrict__ e_aggr, const float* __restrict__ n_aggr,
                              const float* __restrict__ u,
                              const float* __restrict__ gW1, const float* __restrict__ gb1,
                              const float* __restrict__ gW2, const float* __restrict__ gb2,
                              float* __restrict__ u_new)
{
    __shared__ float gin[192];
    __shared__ float hid[256];
    const int g = blockIdx.x, t = threadIdx.x;
    if (t < 64)       gin[t] = e_aggr[g * 64 + t];
    else if (t < 128) gin[t] = n_aggr[g * 64 + (t - 64)];
    else if (t < 192) gin[t] = u[g * 64 + (t - 128)];
    __syncthreads();
    float s = gb1[t];
    #pragma unroll 8
    for (int k = 0; k < 192; ++k) s += gin[k] * gW1[k * 256 + t];
    hid[t] = s > 0.f ? s : 0.f;
    __syncthreads();
    if (t < 64) {
        float o = gb2[t];
        #pragma unroll 8
        for (int k = 0; k < 256; ++k) o += hid[k] * gW2[k * 64 + t];
        u_new[g * 64 + t] = o;
    }
}

// ---------------- workspace layout (bytes) ----------------
#define WS_AGGM_OFF   0u
#define WS_AGGM_BYTES (NN * 64u * 4u)                 // 12,800,000
#define WS_EAGG_OFF   (WS_AGGM_OFF + WS_AGGM_BYTES)   // 12,800,000
#define WS_NAGG_OFF   (WS_EAGG_OFF + GG * 64u * 4u)   // 12,816,384
#define WS_ZERO_BYTES (WS_NAGG_OFF + GG * 64u * 4u)   // 12,832,768 (region to memset 0)
#define WS_W1T_OFF    WS_ZERO_BYTES                   // 65536 shorts
#define WS_W2T_OFF    (WS_W1T_OFF + 65536u * 2u)
#define WS_NW1T_OFF   (WS_W2T_OFF + 16384u * 2u)
#define WS_NW2T_OFF   (WS_NW1T_OFF + 49152u * 2u)     // end: 13,127,680 bytes

extern "C" void kernel_launch(void* const* d_in, const int* in_sizes, int n_in,
                              void* d_out, int out_size, void* d_ws, size_t ws_size,
                              hipStream_t stream) {
    const float* nf  = (const float*)d_in[0];
    const float* ef  = (const float*)d_in[1];
    const float* u   = (const float*)d_in[2];
    const int* src   = (const int*)d_in[3];
    const int* dst   = (const int*)d_in[4];
    const int* ngid  = (const int*)d_in[5];
    const int* egid  = (const int*)d_in[6];
    const float* eW1 = (const float*)d_in[7];
    const float* eb1 = (const float*)d_in[8];
    const float* eW2 = (const float*)d_in[9];
    const float* eb2 = (const float*)d_in[10];
    const float* nW1 = (const float*)d_in[11];
    const float* nb1 = (const float*)d_in[12];
    const float* nW2 = (const float*)d_in[13];
    const float* nb2 = (const float*)d_in[14];
    const float* gW1 = (const float*)d_in[15];
    const float* gb1 = (const float*)d_in[16];
    const float* gW2 = (const float*)d_in[17];
    const float* gb2 = (const float*)d_in[18];

    float* out    = (float*)d_out;
    float* nf_new = out;
    float* ef_new = out + (size_t)NN * DD;
    float* u_new  = out + (size_t)(NN + EE) * DD;

    char* ws = (char*)d_ws;
    float* agg_m  = (float*)(ws + WS_AGGM_OFF);
    float* e_aggr = (float*)(ws + WS_EAGG_OFF);
    float* n_aggr = (float*)(ws + WS_NAGG_OFF);
    short* W1t    = (short*)(ws + WS_W1T_OFF);
    short* W2t    = (short*)(ws + WS_W2T_OFF);
    short* NW1t   = (short*)(ws + WS_NW1T_OFF);
    short* NW2t   = (short*)(ws + WS_NW2T_OFF);

    hipMemsetAsync(d_ws, 0, WS_ZERO_BYTES, stream);
    prep_weights<<<256, 256, 0, stream>>>(eW1, eW2, nW1, nW2, W1t, W2t, NW1t, NW2t);
    edge_kernel<<<EE / 64, 256, 0, stream>>>(nf, ef, u, src, dst, egid,
                                             W1t, eb1, W2t, eb2, ef_new, agg_m, e_aggr);
    node_kernel<<<(NN + 63) / 64, 256, 0, stream>>>(nf, u, ngid, agg_m,
                                                    NW1t, nb1, NW2t, nb2, nf_new, n_aggr);
    global_kernel<<<GG, 256, 0, stream>>>(e_aggr, n_aggr, u, gW1, gb1, gW2, gb2, u_new);
}